// Round 1
// baseline (970.231 us; speedup 1.0000x reference)
//
#include <hip/hip_runtime.h>
#include <math.h>

// Problem constants: B=8, C=128, H=W=64, NC=64, NH=4, HC=16, KS=4,
// Hk=Wk=16, Ns=256, HW=4096, NB=3 blocks: (i,j) = (1,0),(2,0),(2,1)

typedef _Float16 f16x4 __attribute__((ext_vector_type(4)));
typedef float f32x4 __attribute__((ext_vector_type(4)));

// ---------------------------------------------------------------- copy out=x
__global__ __launch_bounds__(256) void k_copy(
    const float* __restrict__ x0, const float* __restrict__ x1,
    const float* __restrict__ x2, float* __restrict__ out) {
  int i = blockIdx.x * 256 + threadIdx.x;       // float4 index, 3*1048576 total
  int lvl = i >> 20;
  int idx = i & 1048575;
  const float4* src = (lvl == 0) ? (const float4*)x0
                    : (lvl == 1) ? (const float4*)x1 : (const float4*)x2;
  ((float4*)out)[i] = src[idx];
}

// ------------------------------------------------- q = pq_w @ x_i[:, :64] + b
__global__ __launch_bounds__(256) void k_qconv(
    const float* __restrict__ x1, const float* __restrict__ x2,
    const float* __restrict__ pq_w, const float* __restrict__ pq_b,
    float* __restrict__ q_buf) {
  int wg = blockIdx.x;
  int tile = wg & 15;
  int b = (wg >> 4) & 7;
  int num = wg >> 7;
  const float* xin = (num == 0) ? x1 : x2;
  const float* xbase = xin + b * 524288;        // channels 0..63 used
  const float* w = pq_w + num * 4096;
  int p0 = tile * 256;
  int lane = threadIdx.x & 63;
  int og = __builtin_amdgcn_readfirstlane(threadIdx.x >> 6);  // 0..3, uniform
  int o0 = og * 16;
  __shared__ float lx[16 * 256];
  float acc[4][16];
#pragma unroll
  for (int j = 0; j < 4; ++j)
#pragma unroll
    for (int i = 0; i < 16; ++i) acc[j][i] = 0.f;
  for (int cc = 0; cc < 64; cc += 16) {
    __syncthreads();
#pragma unroll
    for (int r = 0; r < 4; ++r) {
      int c = (threadIdx.x >> 6) * 4 + r;       // 0..15
      *(float4*)(lx + c * 256 + lane * 4) =
          *(const float4*)(xbase + (cc + c) * 4096 + p0 + lane * 4);
    }
    __syncthreads();
#pragma unroll
    for (int c = 0; c < 16; ++c) {
      float4 xv = *(const float4*)(lx + c * 256 + lane * 4);
#pragma unroll
      for (int i = 0; i < 16; ++i) {
        float wv = w[(o0 + i) * 64 + cc + c];   // uniform -> s_load
        acc[0][i] += xv.x * wv;
        acc[1][i] += xv.y * wv;
        acc[2][i] += xv.z * wv;
        acc[3][i] += xv.w * wv;
      }
    }
  }
  float* qb = q_buf + (num * 8 + b) * 64 * 4096;
#pragma unroll
  for (int i = 0; i < 16; ++i) {
    int o = o0 + i;
    float bias = pq_b[num * 64 + o];
    float4 r;
    r.x = acc[0][i] + bias; r.y = acc[1][i] + bias;
    r.z = acc[2][i] + bias; r.w = acc[3][i] + bias;
    *(float4*)(qb + o * 4096 + p0 + lane * 4) = r;
  }
}

// ---------------- offset head: depthwise 4x4 s4 + LN + GELU + proj -> pos
__global__ __launch_bounds__(256) void k_offset(
    const float* __restrict__ q_buf, const float* __restrict__ dw_w,
    const float* __restrict__ dw_b, const float* __restrict__ ln_g,
    const float* __restrict__ ln_b, const float* __restrict__ pw_w,
    float* __restrict__ pos_buf) {
  int wg = blockIdx.x;
  int num = wg >> 3;
  int n = threadIdx.x;
  int oy = n >> 4, ox = n & 15;
  const float* qb = q_buf + wg * 64 * 4096;
  float off[64];
  float sum = 0.f, sumsq = 0.f;
#pragma unroll
  for (int c = 0; c < 64; ++c) {
    const float* wp = dw_w + (num * 64 + c) * 16;
    const float* qp = qb + c * 4096 + oy * 256 + ox * 4;
    float4 r0 = *(const float4*)(qp);
    float4 r1 = *(const float4*)(qp + 64);
    float4 r2 = *(const float4*)(qp + 128);
    float4 r3 = *(const float4*)(qp + 192);
    float s = dw_b[num * 64 + c];
    s += wp[0] * r0.x + wp[1] * r0.y + wp[2] * r0.z + wp[3] * r0.w;
    s += wp[4] * r1.x + wp[5] * r1.y + wp[6] * r1.z + wp[7] * r1.w;
    s += wp[8] * r2.x + wp[9] * r2.y + wp[10] * r2.z + wp[11] * r2.w;
    s += wp[12] * r3.x + wp[13] * r3.y + wp[14] * r3.z + wp[15] * r3.w;
    off[c] = s;
    sum += s;
    sumsq += s * s;
  }
  float mu = sum * 0.015625f;
  float var = sumsq * 0.015625f - mu * mu;
  float rstd = rsqrtf(var + 1e-5f);
  float offy = 0.f, offx = 0.f;
#pragma unroll
  for (int c = 0; c < 64; ++c) {
    float g = (off[c] - mu) * rstd * ln_g[num * 64 + c] + ln_b[num * 64 + c];
    g = 0.5f * g * (1.f + erff(g * 0.70710678118654752f));  // exact gelu
    offy += pw_w[num * 128 + c] * g;
    offx += pw_w[num * 128 + 64 + c] * g;
  }
  float ref_y = (0.5f + (float)oy) * (2.f / 15.f) - 1.f;
  float ref_x = (0.5f + (float)ox) * (2.f / 15.f) - 1.f;
  float py = fminf(fmaxf(offy + ref_y, -1.f), 1.f);
  float px = fminf(fmaxf(offx + ref_x, -1.f), 1.f);
  pos_buf[(wg * 256 + n) * 2 + 0] = py;
  pos_buf[(wg * 256 + n) * 2 + 1] = px;
}

// ------------- bilinear sample kv (align_corners=True) -> xs[num][b][c][n]
__global__ __launch_bounds__(256) void k_sample(
    const float* __restrict__ x0, const float* __restrict__ x1,
    const float* __restrict__ pos_buf, float* __restrict__ xs_buf) {
  int wg = blockIdx.x;
  int cg = wg & 7;
  int b = (wg >> 3) & 7;
  int num = wg >> 6;
  const float* xj = (num == 2) ? x1 : x0;       // kv source: x0,x0,x1
  int n = threadIdx.x;
  int nb = num * 8 + b;
  float py = pos_buf[(nb * 256 + n) * 2 + 0];
  float px = pos_buf[(nb * 256 + n) * 2 + 1];
  float fy = (py + 1.f) * 31.5f;                // (g+1)*0.5*(64-1)
  float fx = (px + 1.f) * 31.5f;
  float y0f = floorf(fy), x0f = floorf(fx);
  float wy = fy - y0f, wx = fx - x0f;
  int y0 = (int)y0f, xi0 = (int)x0f;
  int y1 = min(y0 + 1, 63), xi1 = min(xi0 + 1, 63);  // OOB tap has weight 0
  float w00 = (1.f - wy) * (1.f - wx), w01 = (1.f - wy) * wx;
  float w10 = wy * (1.f - wx), w11 = wy * wx;
  const float* xb = xj + b * 524288;
#pragma unroll
  for (int cc = 0; cc < 8; ++cc) {
    int c = cg * 8 + cc;
    const float* p = xb + c * 4096;
    float v = w00 * p[y0 * 64 + xi0] + w01 * p[y0 * 64 + xi1] +
              w10 * p[y1 * 64 + xi0] + w11 * p[y1 * 64 + xi1];
    xs_buf[(nb * 64 + c) * 256 + n] = v;
  }
}

// -------------------------------- k = pk_w@xs + pk_b ; v = pv_w@xs + pv_b
__global__ __launch_bounds__(256) void k_kv(
    const float* __restrict__ xs_buf, const float* __restrict__ pk_w,
    const float* __restrict__ pk_b, const float* __restrict__ pv_w,
    const float* __restrict__ pv_b, float* __restrict__ k_buf,
    float* __restrict__ v_buf) {
  int wg = blockIdx.x;
  int which = wg & 1;
  int nb = wg >> 1;
  int num = nb >> 3;
  const float* w = (which ? pv_w : pk_w) + num * 4096;
  const float* bias = (which ? pv_b : pk_b) + num * 64;
  float* ob = (which ? v_buf : k_buf) + nb * 64 * 256;
  const float* xsb = xs_buf + nb * 64 * 256;
  int n = threadIdx.x;
  float acc[64];
#pragma unroll
  for (int o = 0; o < 64; ++o) acc[o] = 0.f;
  for (int c = 0; c < 64; ++c) {
    float xv = xsb[c * 256 + n];
#pragma unroll
    for (int o = 0; o < 64; ++o) acc[o] += w[o * 64 + c] * xv;  // s_loads
  }
#pragma unroll
  for (int o = 0; o < 64; ++o) ob[o * 256 + n] = acc[o] + bias[o];
}

// -------- pad rpe tables 127x127 -> 128x128 (dup last row/col): removes all
// clamp logic in k_attn; taps become base + imm offsets {0,1,128,129}.
// NOTE: tpad ALIASES xs_buf (dead after k_kv) so ws footprint stays at the
// round-0-proven 29.93 MB — growing ws caused the round-2 device fault.
__global__ __launch_bounds__(128) void k_padrpe(
    const float* __restrict__ rpe, float* __restrict__ tpad) {
  int wg = blockIdx.x;              // 12 tables * 128 rows
  int tbl = wg >> 7;
  int r = wg & 127;
  int c = threadIdx.x;
  int rs = min(r, 126), cs = min(c, 126);
  tpad[tbl * 16384 + r * 128 + c] = rpe[tbl * 16129 + rs * 127 + cs];
}

// ----------------- MFMA attention. S^T = K_A . Q_B  (16x16x16 f16):
// C-layout of S^T (n=quad*4+reg, m=lane&15) == B-frag layout for PV
// (O^T = V_A . P^T_B), so no transpose round-trip is needed.
// grid 1536 = num(3)*b(8)*h(4)*mblock(16); 4 waves, each 4 m-tiles of 16.
//
// Round-N change: the bias table window for one block is exactly rows
// [mblock*4, mblock*4+67] x cols [0,127] of the padded table, because
// my - mblock*4 == wave (0..3), mx == mt*16+l15 (0..63), iy,ix in [0,63].
// Stage those 68x128 floats (34.8 KB) in LDS once; all 4096 bias taps per
// wave become ds_read2_b32 pairs (quads read 16 consecutive floats ->
// <=2 lanes/bank, conflict-free), and tap addressing collapses to one
// 32-bit LDS offset precomputed in s_kp. __launch_bounds__(256,3) caps
// VGPR at ~170 so 3 blocks/CU (12 waves) are resident vs 2 before.
__global__ __launch_bounds__(256, 3) void k_attn(
    float* __restrict__ q_buf, const float* __restrict__ k_buf,
    const float* __restrict__ v_buf, const float* __restrict__ pos_buf,
    const float* __restrict__ tpad) {
  int wg = blockIdx.x;
  int mblock = wg & 15;
  int h = (wg >> 4) & 3;
  int b = (wg >> 6) & 7;
  int num = wg >> 9;
  int nb = num * 8 + b;
  int tid = threadIdx.x;
  int lane = tid & 63;
  int wave = __builtin_amdgcn_readfirstlane(tid >> 6);
  int l15 = lane & 15;
  int quad = lane >> 4;

  __shared__ float4 s_kp[256];
  __shared__ __align__(16) float s_T[68 * 128];   // 34,816 B

  // stage the block's table window: rows mblock*4 .. mblock*4+67 (68x128).
  // Base is a multiple of 512 floats -> 16B aligned; max source index is
  // 11*16384 + 15*512 + 8704 = 196608 = tpad size exactly.
  {
    const float4* Ts = (const float4*)(tpad + (num * 4 + h) * 16384 + mblock * 512);
    float4* Td = (float4*)s_T;
#pragma unroll
    for (int i = 0; i < 8; ++i) Td[tid + i * 256] = Ts[tid + i * 256];
    if (tid < 128) Td[tid + 2048] = Ts[tid + 2048];   // 2176 = 8.5*256
  }

  // per-key bilinear params: table coord t = m + 31.5*(1-pos); store the
  // tap's float offset iy*128+ix (int bits) + fractional weights.
  {
    float py = pos_buf[(nb * 256 + tid) * 2 + 0];
    float px = pos_buf[(nb * 256 + tid) * 2 + 1];
    float by = 31.5f * (1.f - py);
    float bx = 31.5f * (1.f - px);
    float iyf = floorf(by), ixf = floorf(bx);
    float4 kp;
    kp.x = __int_as_float((int)iyf * 128 + (int)ixf);
    kp.y = by - iyf;                  // wy
    kp.z = bx - ixf;                  // wx
    kp.w = 0.f;
    s_kp[tid] = kp;
  }
  __syncthreads();

  int hc = nb * 64 + h * 16;
  const float* kb = k_buf + hc * 256;
  const float* vb = v_buf + hc * 256;
  float* qb = q_buf + hc * 4096;

  // K frags: A[n][c]: n = l15 + 16t, c = quad*4+j  (reused across 4 m-tiles)
  // V frags: A[c][n]: c = l15, n = 16t + quad*4+j  -> contiguous float4
  f16x4 kf[16], vf[16];
#pragma unroll
  for (int t = 0; t < 16; ++t) {
    int n = t * 16 + l15;
#pragma unroll
    for (int j = 0; j < 4; ++j)
      kf[t][j] = (_Float16)kb[(quad * 4 + j) * 256 + n];
    float4 vv = *(const float4*)(vb + l15 * 256 + t * 16 + quad * 4);
    vf[t][0] = (_Float16)vv.x; vf[t][1] = (_Float16)vv.y;
    vf[t][2] = (_Float16)vv.z; vf[t][3] = (_Float16)vv.w;
  }

#pragma unroll 1
  for (int mt = 0; mt < 4; ++mt) {
    int m = mblock * 256 + wave * 64 + mt * 16 + l15;
    // my - mblock*4 == wave; mx == mt*16 + l15 -> LDS row/col directly.
    const float* Trow = s_T + wave * 128 + mt * 16 + l15;
    // Q frag: B[c][m]: m = l15, c = quad*4+j
    f16x4 qf;
#pragma unroll
    for (int j = 0; j < 4; ++j)
      qf[j] = (_Float16)qb[(quad * 4 + j) * 4096 + m];

    f32x4 O = {0.f, 0.f, 0.f, 0.f};
    float L = 0.f;
#pragma unroll
    for (int t = 0; t < 16; ++t) {
      f32x4 Z = {0.f, 0.f, 0.f, 0.f};
      f32x4 S = __builtin_amdgcn_mfma_f32_16x16x16f16(kf[t], qf, Z, 0, 0, 0);
      f16x4 pf;
#pragma unroll
      for (int r = 0; r < 4; ++r) {
        float4 kp = s_kp[t * 16 + quad * 4 + r];
        const float* p = Trow + __float_as_int(kp.x);
        float t00 = p[0], t01 = p[1], t10 = p[128], t11 = p[129];
        float lx0 = fmaf(kp.z, t01 - t00, t00);
        float lx1 = fmaf(kp.z, t11 - t10, t10);
        float bias = fmaf(kp.y, lx1 - lx0, lx0);
        float s = fminf(fmaf(S[r], 0.25f, bias), 10.f);  // logits << 10 here
        float e = __expf(s);
        L += e;
        pf[r] = (_Float16)e;
      }
      O = __builtin_amdgcn_mfma_f32_16x16x16f16(vf[t], pf, O, 0, 0, 0);
    }
    L += __shfl_xor(L, 16);
    L += __shfl_xor(L, 32);
    float rinv = 1.f / L;
#pragma unroll
    for (int r = 0; r < 4; ++r)
      qb[(quad * 4 + r) * 4096 + m] = O[r] * rinv;  // in-place over q
  }
}

// ------------------- po conv, accumulate into out[l][b][64+o][p]
__global__ __launch_bounds__(256) void k_po(
    const float* __restrict__ attn_buf, const float* __restrict__ po_w,
    const float* __restrict__ po_b, float* __restrict__ out) {
  int wg = blockIdx.x;
  int tile = wg & 15;
  int b = (wg >> 4) & 7;
  int num = wg >> 7;
  int l = (num == 0) ? 1 : 2;
  const float* abase = attn_buf + (num * 8 + b) * 64 * 4096;
  const float* w = po_w + num * 4096;
  int p0 = tile * 256;
  int lane = threadIdx.x & 63;
  int og = __builtin_amdgcn_readfirstlane(threadIdx.x >> 6);
  int o0 = og * 16;
  __shared__ float lx[16 * 256];
  float acc[4][16];
#pragma unroll
  for (int j = 0; j < 4; ++j)
#pragma unroll
    for (int i = 0; i < 16; ++i) acc[j][i] = 0.f;
  for (int cc = 0; cc < 64; cc += 16) {
    __syncthreads();
#pragma unroll
    for (int r = 0; r < 4; ++r) {
      int c = (threadIdx.x >> 6) * 4 + r;
      *(float4*)(lx + c * 256 + lane * 4) =
          *(const float4*)(abase + (cc + c) * 4096 + p0 + lane * 4);
    }
    __syncthreads();
#pragma unroll
    for (int c = 0; c < 16; ++c) {
      float4 xv = *(const float4*)(lx + c * 256 + lane * 4);
#pragma unroll
      for (int i = 0; i < 16; ++i) {
        float wv = w[(o0 + i) * 64 + cc + c];
        acc[0][i] += xv.x * wv;
        acc[1][i] += xv.y * wv;
        acc[2][i] += xv.z * wv;
        acc[3][i] += xv.w * wv;
      }
    }
  }
  float* ob = out + ((l * 8 + b) * 128 + 64) * 4096;
#pragma unroll
  for (int i = 0; i < 16; ++i) {
    int o = o0 + i;
    float bias = po_b[num * 64 + o];
#pragma unroll
    for (int j = 0; j < 4; ++j) {
      atomicAdd(&ob[o * 4096 + p0 + lane * 4 + j], acc[j][i] + bias);
    }
  }
}

extern "C" void kernel_launch(void* const* d_in, const int* in_sizes, int n_in,
                              void* d_out, int out_size, void* d_ws,
                              size_t ws_size, hipStream_t stream) {
  const float* x0 = (const float*)d_in[0];
  const float* x1 = (const float*)d_in[1];
  const float* x2 = (const float*)d_in[2];
  const float* pq_w = (const float*)d_in[3];
  const float* pq_b = (const float*)d_in[4];
  const float* dw_w = (const float*)d_in[5];
  const float* dw_b = (const float*)d_in[6];
  const float* ln_g = (const float*)d_in[7];
  const float* ln_b = (const float*)d_in[8];
  const float* pw_w = (const float*)d_in[9];
  const float* pk_w = (const float*)d_in[10];
  const float* pk_b = (const float*)d_in[11];
  const float* pv_w = (const float*)d_in[12];
  const float* pv_b = (const float*)d_in[13];
  const float* po_w = (const float*)d_in[14];
  const float* po_b = (const float*)d_in[15];
  const float* rpe = (const float*)d_in[16];
  float* out = (float*)d_out;
  float* ws = (float*)d_ws;

  // ws layout (floats): q/attn (in-place) 6291456, pos 12288, xs 393216,
  // k 393216, v 393216 -> 29,933,568 bytes, IDENTICAL to round-0-proven size.
  // tpad (196608) aliases xs_buf: xs is dead after k_kv; k_padrpe runs after.
  float* q_buf = ws;
  float* pos_buf = q_buf + 6291456;
  float* xs_buf = pos_buf + 12288;
  float* k_buf = xs_buf + 393216;
  float* v_buf = k_buf + 393216;
  float* tpad = xs_buf;

  hipLaunchKernelGGL(k_copy, dim3(12288), dim3(256), 0, stream, x0, x1, x2, out);
  hipLaunchKernelGGL(k_qconv, dim3(384), dim3(256), 0, stream, x1, x2, pq_w,
                     pq_b, q_buf);
  hipLaunchKernelGGL(k_offset, dim3(24), dim3(256), 0, stream, q_buf, dw_w,
                     dw_b, ln_g, ln_b, pw_w, pos_buf);
  hipLaunchKernelGGL(k_sample, dim3(192), dim3(256), 0, stream, x0, x1,
                     pos_buf, xs_buf);
  hipLaunchKernelGGL(k_kv, dim3(48), dim3(256), 0, stream, xs_buf, pk_w, pk_b,
                     pv_w, pv_b, k_buf, v_buf);
  hipLaunchKernelGGL(k_padrpe, dim3(1536), dim3(128), 0, stream, rpe, tpad);
  hipLaunchKernelGGL(k_attn, dim3(1536), dim3(256), 0, stream, q_buf, k_buf,
                     v_buf, pos_buf, tpad);
  hipLaunchKernelGGL(k_po, dim3(384), dim3(256), 0, stream, q_buf, po_w, po_b,
                     out);
}

// Round 2
// 419.434 us; speedup vs baseline: 2.3132x; 2.3132x over previous
//
#include <hip/hip_runtime.h>
#include <math.h>

// Problem constants: B=8, C=128, H=W=64, NC=64, NH=4, HC=16, KS=4,
// Hk=Wk=16, Ns=256, HW=4096, NB=3 blocks: (i,j) = (1,0),(2,0),(2,1)

typedef _Float16 f16x4 __attribute__((ext_vector_type(4)));
typedef float f32x4 __attribute__((ext_vector_type(4)));

// ---------------------------------------------------------------- copy out=x
__global__ __launch_bounds__(256) void k_copy(
    const float* __restrict__ x0, const float* __restrict__ x1,
    const float* __restrict__ x2, float* __restrict__ out) {
  int i = blockIdx.x * 256 + threadIdx.x;       // float4 index, 3*1048576 total
  int lvl = i >> 20;
  int idx = i & 1048575;
  const float4* src = (lvl == 0) ? (const float4*)x0
                    : (lvl == 1) ? (const float4*)x1 : (const float4*)x2;
  ((float4*)out)[i] = src[idx];
}

// ------------------------------------------------- q = pq_w @ x_i[:, :64] + b
__global__ __launch_bounds__(256) void k_qconv(
    const float* __restrict__ x1, const float* __restrict__ x2,
    const float* __restrict__ pq_w, const float* __restrict__ pq_b,
    float* __restrict__ q_buf) {
  int wg = blockIdx.x;
  int tile = wg & 15;
  int b = (wg >> 4) & 7;
  int num = wg >> 7;
  const float* xin = (num == 0) ? x1 : x2;
  const float* xbase = xin + b * 524288;        // channels 0..63 used
  const float* w = pq_w + num * 4096;
  int p0 = tile * 256;
  int lane = threadIdx.x & 63;
  int og = __builtin_amdgcn_readfirstlane(threadIdx.x >> 6);  // 0..3, uniform
  int o0 = og * 16;
  __shared__ float lx[16 * 256];
  float acc[4][16];
#pragma unroll
  for (int j = 0; j < 4; ++j)
#pragma unroll
    for (int i = 0; i < 16; ++i) acc[j][i] = 0.f;
  for (int cc = 0; cc < 64; cc += 16) {
    __syncthreads();
#pragma unroll
    for (int r = 0; r < 4; ++r) {
      int c = (threadIdx.x >> 6) * 4 + r;       // 0..15
      *(float4*)(lx + c * 256 + lane * 4) =
          *(const float4*)(xbase + (cc + c) * 4096 + p0 + lane * 4);
    }
    __syncthreads();
#pragma unroll
    for (int c = 0; c < 16; ++c) {
      float4 xv = *(const float4*)(lx + c * 256 + lane * 4);
#pragma unroll
      for (int i = 0; i < 16; ++i) {
        float wv = w[(o0 + i) * 64 + cc + c];   // uniform -> s_load
        acc[0][i] += xv.x * wv;
        acc[1][i] += xv.y * wv;
        acc[2][i] += xv.z * wv;
        acc[3][i] += xv.w * wv;
      }
    }
  }
  float* qb = q_buf + (num * 8 + b) * 64 * 4096;
#pragma unroll
  for (int i = 0; i < 16; ++i) {
    int o = o0 + i;
    float bias = pq_b[num * 64 + o];
    float4 r;
    r.x = acc[0][i] + bias; r.y = acc[1][i] + bias;
    r.z = acc[2][i] + bias; r.w = acc[3][i] + bias;
    *(float4*)(qb + o * 4096 + p0 + lane * 4) = r;
  }
}

// ---------------- offset head: depthwise 4x4 s4 + LN + GELU + proj -> pos
__global__ __launch_bounds__(256) void k_offset(
    const float* __restrict__ q_buf, const float* __restrict__ dw_w,
    const float* __restrict__ dw_b, const float* __restrict__ ln_g,
    const float* __restrict__ ln_b, const float* __restrict__ pw_w,
    float* __restrict__ pos_buf) {
  int wg = blockIdx.x;
  int num = wg >> 3;
  int n = threadIdx.x;
  int oy = n >> 4, ox = n & 15;
  const float* qb = q_buf + wg * 64 * 4096;
  float off[64];
  float sum = 0.f, sumsq = 0.f;
#pragma unroll
  for (int c = 0; c < 64; ++c) {
    const float* wp = dw_w + (num * 64 + c) * 16;
    const float* qp = qb + c * 4096 + oy * 256 + ox * 4;
    float4 r0 = *(const float4*)(qp);
    float4 r1 = *(const float4*)(qp + 64);
    float4 r2 = *(const float4*)(qp + 128);
    float4 r3 = *(const float4*)(qp + 192);
    float s = dw_b[num * 64 + c];
    s += wp[0] * r0.x + wp[1] * r0.y + wp[2] * r0.z + wp[3] * r0.w;
    s += wp[4] * r1.x + wp[5] * r1.y + wp[6] * r1.z + wp[7] * r1.w;
    s += wp[8] * r2.x + wp[9] * r2.y + wp[10] * r2.z + wp[11] * r2.w;
    s += wp[12] * r3.x + wp[13] * r3.y + wp[14] * r3.z + wp[15] * r3.w;
    off[c] = s;
    sum += s;
    sumsq += s * s;
  }
  float mu = sum * 0.015625f;
  float var = sumsq * 0.015625f - mu * mu;
  float rstd = rsqrtf(var + 1e-5f);
  float offy = 0.f, offx = 0.f;
#pragma unroll
  for (int c = 0; c < 64; ++c) {
    float g = (off[c] - mu) * rstd * ln_g[num * 64 + c] + ln_b[num * 64 + c];
    g = 0.5f * g * (1.f + erff(g * 0.70710678118654752f));  // exact gelu
    offy += pw_w[num * 128 + c] * g;
    offx += pw_w[num * 128 + 64 + c] * g;
  }
  float ref_y = (0.5f + (float)oy) * (2.f / 15.f) - 1.f;
  float ref_x = (0.5f + (float)ox) * (2.f / 15.f) - 1.f;
  float py = fminf(fmaxf(offy + ref_y, -1.f), 1.f);
  float px = fminf(fmaxf(offx + ref_x, -1.f), 1.f);
  pos_buf[(wg * 256 + n) * 2 + 0] = py;
  pos_buf[(wg * 256 + n) * 2 + 1] = px;
}

// ------------- bilinear sample kv (align_corners=True) -> xs[num][b][c][n]
__global__ __launch_bounds__(256) void k_sample(
    const float* __restrict__ x0, const float* __restrict__ x1,
    const float* __restrict__ pos_buf, float* __restrict__ xs_buf) {
  int wg = blockIdx.x;
  int cg = wg & 7;
  int b = (wg >> 3) & 7;
  int num = wg >> 6;
  const float* xj = (num == 2) ? x1 : x0;       // kv source: x0,x0,x1
  int n = threadIdx.x;
  int nb = num * 8 + b;
  float py = pos_buf[(nb * 256 + n) * 2 + 0];
  float px = pos_buf[(nb * 256 + n) * 2 + 1];
  float fy = (py + 1.f) * 31.5f;                // (g+1)*0.5*(64-1)
  float fx = (px + 1.f) * 31.5f;
  float y0f = floorf(fy), x0f = floorf(fx);
  float wy = fy - y0f, wx = fx - x0f;
  int y0 = (int)y0f, xi0 = (int)x0f;
  int y1 = min(y0 + 1, 63), xi1 = min(xi0 + 1, 63);  // OOB tap has weight 0
  float w00 = (1.f - wy) * (1.f - wx), w01 = (1.f - wy) * wx;
  float w10 = wy * (1.f - wx), w11 = wy * wx;
  const float* xb = xj + b * 524288;
#pragma unroll
  for (int cc = 0; cc < 8; ++cc) {
    int c = cg * 8 + cc;
    const float* p = xb + c * 4096;
    float v = w00 * p[y0 * 64 + xi0] + w01 * p[y0 * 64 + xi1] +
              w10 * p[y1 * 64 + xi0] + w11 * p[y1 * 64 + xi1];
    xs_buf[(nb * 64 + c) * 256 + n] = v;
  }
}

// -------------------------------- k = pk_w@xs + pk_b ; v = pv_w@xs + pv_b
__global__ __launch_bounds__(256) void k_kv(
    const float* __restrict__ xs_buf, const float* __restrict__ pk_w,
    const float* __restrict__ pk_b, const float* __restrict__ pv_w,
    const float* __restrict__ pv_b, float* __restrict__ k_buf,
    float* __restrict__ v_buf) {
  int wg = blockIdx.x;
  int which = wg & 1;
  int nb = wg >> 1;
  int num = nb >> 3;
  const float* w = (which ? pv_w : pk_w) + num * 4096;
  const float* bias = (which ? pv_b : pk_b) + num * 64;
  float* ob = (which ? v_buf : k_buf) + nb * 64 * 256;
  const float* xsb = xs_buf + nb * 64 * 256;
  int n = threadIdx.x;
  float acc[64];
#pragma unroll
  for (int o = 0; o < 64; ++o) acc[o] = 0.f;
  for (int c = 0; c < 64; ++c) {
    float xv = xsb[c * 256 + n];
#pragma unroll
    for (int o = 0; o < 64; ++o) acc[o] += w[o * 64 + c] * xv;  // s_loads
  }
#pragma unroll
  for (int o = 0; o < 64; ++o) ob[o * 256 + n] = acc[o] + bias[o];
}

// -------- pad rpe tables 127x127 -> 128x128 (dup last row/col): removes all
// clamp logic in k_attn; taps become base + imm offsets.
// NOTE: tpad ALIASES xs_buf (dead after k_kv) so ws footprint stays at the
// round-0-proven 29.93 MB — growing ws caused the round-2 device fault.
__global__ __launch_bounds__(128) void k_padrpe(
    const float* __restrict__ rpe, float* __restrict__ tpad) {
  int wg = blockIdx.x;              // 12 tables * 128 rows
  int tbl = wg >> 7;
  int r = wg & 127;
  int c = threadIdx.x;
  int rs = min(r, 126), cs = min(c, 126);
  tpad[tbl * 16384 + r * 128 + c] = rpe[tbl * 16129 + rs * 127 + cs];
}

// ----------------- MFMA attention. S^T = K_A . Q_B  (16x16x16 f16):
// C-layout of S^T (n=quad*4+reg, m=lane&15) == B-frag layout for PV
// (O^T = V_A . P^T_B), so no transpose round-trip is needed.
// grid 1536 = num(3)*b(8)*h(4)*mblock(16); 4 waves, each 4 m-tiles of 16.
//
// Bias table: this block touches exactly rows [mblock*4, mblock*4+67] x
// cols [0,127] of the padded table (my-mblock*4==wave, mx==mt*16+l15,
// iy,ix in [0,63]); stage that 68x128 window in LDS with row stride
// padded to 132 floats (33 float4 -> 16B-aligned rows, and bank =
// (4*(wave+iy)+col)&31 decorrelates the 4 quads' tap runs).
//
// Round-2 lesson: forcing __launch_bounds__(256,3) with persistent
// kf[16]/vf[16] arrays spilled 64 VGPRs to scratch (WRITE_SIZE 24MB->530MB,
// 2.5x regression). Fix is structural: LOOP INTERCHANGE (t outer, mt inner)
// so no 16-entry fragment array persists. Per-t state: one kf + one vf;
// persistent: qf[4]+O[4]+L[4] (~28 regs), all statically indexed.
// No forced occupancy cap.
__global__ __launch_bounds__(256) void k_attn(
    float* __restrict__ q_buf, const float* __restrict__ k_buf,
    const float* __restrict__ v_buf, const float* __restrict__ pos_buf,
    const float* __restrict__ tpad) {
  int wg = blockIdx.x;
  int mblock = wg & 15;
  int h = (wg >> 4) & 3;
  int b = (wg >> 6) & 7;
  int num = wg >> 9;
  int nb = num * 8 + b;
  int tid = threadIdx.x;
  int lane = tid & 63;
  int wave = __builtin_amdgcn_readfirstlane(tid >> 6);
  int l15 = lane & 15;
  int quad = lane >> 4;

  __shared__ float4 s_kp[256];
  __shared__ __align__(16) float s_T[68 * 132];   // 35,904 B

  // stage the block's table window: rows mblock*4 .. mblock*4+67 (68x128),
  // dst stride 132. Source base is a multiple of 512 floats -> 16B aligned;
  // max source float idx = 11*16384 + 15*512 + 8703 = 196607 (tpad end).
  {
    const float4* Ts = (const float4*)(tpad + (num * 4 + h) * 16384 + mblock * 512);
    float4* Td = (float4*)s_T;
#pragma unroll
    for (int i = 0; i < 8; ++i) {
      int idx = tid + i * 256;
      Td[idx + (idx >> 5)] = Ts[idx];    // row*33 + col32
    }
    if (tid < 128) {
      int idx = tid + 2048;              // 2176 = 8.5*256 total
      Td[idx + (idx >> 5)] = Ts[idx];
    }
  }

  // per-key bilinear params: table coord t = m + 31.5*(1-pos); store the
  // tap's LDS float offset iy*132+ix (int bits) + fractional weights.
  {
    float py = pos_buf[(nb * 256 + tid) * 2 + 0];
    float px = pos_buf[(nb * 256 + tid) * 2 + 1];
    float by = 31.5f * (1.f - py);
    float bx = 31.5f * (1.f - px);
    float iyf = floorf(by), ixf = floorf(bx);
    float4 kp;
    kp.x = __int_as_float((int)iyf * 132 + (int)ixf);
    kp.y = by - iyf;                  // wy
    kp.z = bx - ixf;                  // wx
    kp.w = 0.f;
    s_kp[tid] = kp;
  }
  __syncthreads();

  int hc = nb * 64 + h * 16;
  const float* kb = k_buf + hc * 256;
  const float* vb = v_buf + hc * 256;
  float* qb = q_buf + hc * 4096;
  const float* Trow = s_T + wave * 132 + l15;   // + mt*16 + tap offset

  // persistent per-mt state (statically indexed everywhere)
  f16x4 qf[4];
  f32x4 O[4];
  float L[4];
#pragma unroll
  for (int mt = 0; mt < 4; ++mt) {
    int m = mblock * 256 + wave * 64 + mt * 16 + l15;
#pragma unroll
    for (int j = 0; j < 4; ++j)
      qf[mt][j] = (_Float16)qb[(quad * 4 + j) * 4096 + m];  // B[c][m]
    O[mt][0] = 0.f; O[mt][1] = 0.f; O[mt][2] = 0.f; O[mt][3] = 0.f;
    L[mt] = 0.f;
  }

#pragma unroll 2
  for (int t = 0; t < 16; ++t) {
    // K frag: A[n][c]: n = t*16 + l15, c = quad*4+j
    f16x4 kf;
#pragma unroll
    for (int j = 0; j < 4; ++j)
      kf[j] = (_Float16)kb[(quad * 4 + j) * 256 + t * 16 + l15];
    // V frag: A[c][n]: c = l15, n = t*16 + quad*4+j -> contiguous float4
    float4 vv = *(const float4*)(vb + l15 * 256 + t * 16 + quad * 4);
    f16x4 vf;
    vf[0] = (_Float16)vv.x; vf[1] = (_Float16)vv.y;
    vf[2] = (_Float16)vv.z; vf[3] = (_Float16)vv.w;

    f32x4 S[4];
#pragma unroll
    for (int mt = 0; mt < 4; ++mt) {
      f32x4 Z = {0.f, 0.f, 0.f, 0.f};
      S[mt] = __builtin_amdgcn_mfma_f32_16x16x16f16(kf, qf[mt], Z, 0, 0, 0);
    }

    f16x4 pf[4];
#pragma unroll
    for (int r = 0; r < 4; ++r) {
      float4 kp = s_kp[t * 16 + quad * 4 + r];
      int off = __float_as_int(kp.x);
#pragma unroll
      for (int mt = 0; mt < 4; ++mt) {
        const float* p = Trow + mt * 16 + off;
        float t00 = p[0], t01 = p[1], t10 = p[132], t11 = p[133];
        float lx0 = fmaf(kp.z, t01 - t00, t00);
        float lx1 = fmaf(kp.z, t11 - t10, t10);
        float bias = fmaf(kp.y, lx1 - lx0, lx0);
        float s = fminf(fmaf(S[mt][r], 0.25f, bias), 10.f);  // logits << 10
        float e = __expf(s);
        L[mt] += e;
        pf[mt][r] = (_Float16)e;
      }
    }
#pragma unroll
    for (int mt = 0; mt < 4; ++mt)
      O[mt] = __builtin_amdgcn_mfma_f32_16x16x16f16(vf, pf[mt], O[mt], 0, 0, 0);
  }

#pragma unroll
  for (int mt = 0; mt < 4; ++mt) {
    float Lm = L[mt];
    Lm += __shfl_xor(Lm, 16);
    Lm += __shfl_xor(Lm, 32);
    float rinv = 1.f / Lm;
    int m = mblock * 256 + wave * 64 + mt * 16 + l15;
#pragma unroll
    for (int r = 0; r < 4; ++r)
      qb[(quad * 4 + r) * 4096 + m] = O[mt][r] * rinv;  // in-place over q
  }
}

// ------------------- po conv, accumulate into out[l][b][64+o][p]
__global__ __launch_bounds__(256) void k_po(
    const float* __restrict__ attn_buf, const float* __restrict__ po_w,
    const float* __restrict__ po_b, float* __restrict__ out) {
  int wg = blockIdx.x;
  int tile = wg & 15;
  int b = (wg >> 4) & 7;
  int num = wg >> 7;
  int l = (num == 0) ? 1 : 2;
  const float* abase = attn_buf + (num * 8 + b) * 64 * 4096;
  const float* w = po_w + num * 4096;
  int p0 = tile * 256;
  int lane = threadIdx.x & 63;
  int og = __builtin_amdgcn_readfirstlane(threadIdx.x >> 6);
  int o0 = og * 16;
  __shared__ float lx[16 * 256];
  float acc[4][16];
#pragma unroll
  for (int j = 0; j < 4; ++j)
#pragma unroll
    for (int i = 0; i < 16; ++i) acc[j][i] = 0.f;
  for (int cc = 0; cc < 64; cc += 16) {
    __syncthreads();
#pragma unroll
    for (int r = 0; r < 4; ++r) {
      int c = (threadIdx.x >> 6) * 4 + r;
      *(float4*)(lx + c * 256 + lane * 4) =
          *(const float4*)(abase + (cc + c) * 4096 + p0 + lane * 4);
    }
    __syncthreads();
#pragma unroll
    for (int c = 0; c < 16; ++c) {
      float4 xv = *(const float4*)(lx + c * 256 + lane * 4);
#pragma unroll
      for (int i = 0; i < 16; ++i) {
        float wv = w[(o0 + i) * 64 + cc + c];
        acc[0][i] += xv.x * wv;
        acc[1][i] += xv.y * wv;
        acc[2][i] += xv.z * wv;
        acc[3][i] += xv.w * wv;
      }
    }
  }
  float* ob = out + ((l * 8 + b) * 128 + 64) * 4096;
#pragma unroll
  for (int i = 0; i < 16; ++i) {
    int o = o0 + i;
    float bias = po_b[num * 64 + o];
#pragma unroll
    for (int j = 0; j < 4; ++j) {
      atomicAdd(&ob[o * 4096 + p0 + lane * 4 + j], acc[j][i] + bias);
    }
  }
}

extern "C" void kernel_launch(void* const* d_in, const int* in_sizes, int n_in,
                              void* d_out, int out_size, void* d_ws,
                              size_t ws_size, hipStream_t stream) {
  const float* x0 = (const float*)d_in[0];
  const float* x1 = (const float*)d_in[1];
  const float* x2 = (const float*)d_in[2];
  const float* pq_w = (const float*)d_in[3];
  const float* pq_b = (const float*)d_in[4];
  const float* dw_w = (const float*)d_in[5];
  const float* dw_b = (const float*)d_in[6];
  const float* ln_g = (const float*)d_in[7];
  const float* ln_b = (const float*)d_in[8];
  const float* pw_w = (const float*)d_in[9];
  const float* pk_w = (const float*)d_in[10];
  const float* pk_b = (const float*)d_in[11];
  const float* pv_w = (const float*)d_in[12];
  const float* pv_b = (const float*)d_in[13];
  const float* po_w = (const float*)d_in[14];
  const float* po_b = (const float*)d_in[15];
  const float* rpe = (const float*)d_in[16];
  float* out = (float*)d_out;
  float* ws = (float*)d_ws;

  // ws layout (floats): q/attn (in-place) 6291456, pos 12288, xs 393216,
  // k 393216, v 393216 -> 29,933,568 bytes, IDENTICAL to round-0-proven size.
  // tpad (196608) aliases xs_buf: xs is dead after k_kv; k_padrpe runs after.
  float* q_buf = ws;
  float* pos_buf = q_buf + 6291456;
  float* xs_buf = pos_buf + 12288;
  float* k_buf = xs_buf + 393216;
  float* v_buf = k_buf + 393216;
  float* tpad = xs_buf;

  hipLaunchKernelGGL(k_copy, dim3(12288), dim3(256), 0, stream, x0, x1, x2, out);
  hipLaunchKernelGGL(k_qconv, dim3(384), dim3(256), 0, stream, x1, x2, pq_w,
                     pq_b, q_buf);
  hipLaunchKernelGGL(k_offset, dim3(24), dim3(256), 0, stream, q_buf, dw_w,
                     dw_b, ln_g, ln_b, pw_w, pos_buf);
  hipLaunchKernelGGL(k_sample, dim3(192), dim3(256), 0, stream, x0, x1,
                     pos_buf, xs_buf);
  hipLaunchKernelGGL(k_kv, dim3(48), dim3(256), 0, stream, xs_buf, pk_w, pk_b,
                     pv_w, pv_b, k_buf, v_buf);
  hipLaunchKernelGGL(k_padrpe, dim3(1536), dim3(128), 0, stream, rpe, tpad);
  hipLaunchKernelGGL(k_attn, dim3(1536), dim3(256), 0, stream, q_buf, k_buf,
                     v_buf, pos_buf, tpad);
  hipLaunchKernelGGL(k_po, dim3(384), dim3(256), 0, stream, q_buf, po_w, po_b,
                     out);
}

// Round 3
// 400.845 us; speedup vs baseline: 2.4205x; 1.0464x over previous
//
#include <hip/hip_runtime.h>
#include <math.h>

// Problem constants: B=8, C=128, H=W=64, NC=64, NH=4, HC=16, KS=4,
// Hk=Wk=16, Ns=256, HW=4096, NB=3 blocks: (i,j) = (1,0),(2,0),(2,1)

typedef _Float16 f16x4 __attribute__((ext_vector_type(4)));
typedef float f32x4 __attribute__((ext_vector_type(4)));

// ---------------------------------------------------------------- copy out=x
__global__ __launch_bounds__(256) void k_copy(
    const float* __restrict__ x0, const float* __restrict__ x1,
    const float* __restrict__ x2, float* __restrict__ out) {
  int i = blockIdx.x * 256 + threadIdx.x;       // float4 index, 3*1048576 total
  int lvl = i >> 20;
  int idx = i & 1048575;
  const float4* src = (lvl == 0) ? (const float4*)x0
                    : (lvl == 1) ? (const float4*)x1 : (const float4*)x2;
  ((float4*)out)[i] = src[idx];
}

// ------------------------------------------------- q = pq_w @ x_i[:, :64] + b
__global__ __launch_bounds__(256) void k_qconv(
    const float* __restrict__ x1, const float* __restrict__ x2,
    const float* __restrict__ pq_w, const float* __restrict__ pq_b,
    float* __restrict__ q_buf) {
  int wg = blockIdx.x;
  int tile = wg & 15;
  int b = (wg >> 4) & 7;
  int num = wg >> 7;
  const float* xin = (num == 0) ? x1 : x2;
  const float* xbase = xin + b * 524288;        // channels 0..63 used
  const float* w = pq_w + num * 4096;
  int p0 = tile * 256;
  int lane = threadIdx.x & 63;
  int og = __builtin_amdgcn_readfirstlane(threadIdx.x >> 6);  // 0..3, uniform
  int o0 = og * 16;
  __shared__ float lx[16 * 256];
  float acc[4][16];
#pragma unroll
  for (int j = 0; j < 4; ++j)
#pragma unroll
    for (int i = 0; i < 16; ++i) acc[j][i] = 0.f;
  for (int cc = 0; cc < 64; cc += 16) {
    __syncthreads();
#pragma unroll
    for (int r = 0; r < 4; ++r) {
      int c = (threadIdx.x >> 6) * 4 + r;       // 0..15
      *(float4*)(lx + c * 256 + lane * 4) =
          *(const float4*)(xbase + (cc + c) * 4096 + p0 + lane * 4);
    }
    __syncthreads();
#pragma unroll
    for (int c = 0; c < 16; ++c) {
      float4 xv = *(const float4*)(lx + c * 256 + lane * 4);
#pragma unroll
      for (int i = 0; i < 16; ++i) {
        float wv = w[(o0 + i) * 64 + cc + c];   // uniform -> s_load
        acc[0][i] += xv.x * wv;
        acc[1][i] += xv.y * wv;
        acc[2][i] += xv.z * wv;
        acc[3][i] += xv.w * wv;
      }
    }
  }
  float* qb = q_buf + (num * 8 + b) * 64 * 4096;
#pragma unroll
  for (int i = 0; i < 16; ++i) {
    int o = o0 + i;
    float bias = pq_b[num * 64 + o];
    float4 r;
    r.x = acc[0][i] + bias; r.y = acc[1][i] + bias;
    r.z = acc[2][i] + bias; r.w = acc[3][i] + bias;
    *(float4*)(qb + o * 4096 + p0 + lane * 4) = r;
  }
}

// ---------------- offset head: depthwise 4x4 s4 + LN + GELU + proj -> pos
__global__ __launch_bounds__(256) void k_offset(
    const float* __restrict__ q_buf, const float* __restrict__ dw_w,
    const float* __restrict__ dw_b, const float* __restrict__ ln_g,
    const float* __restrict__ ln_b, const float* __restrict__ pw_w,
    float* __restrict__ pos_buf) {
  int wg = blockIdx.x;
  int num = wg >> 3;
  int n = threadIdx.x;
  int oy = n >> 4, ox = n & 15;
  const float* qb = q_buf + wg * 64 * 4096;
  float off[64];
  float sum = 0.f, sumsq = 0.f;
#pragma unroll
  for (int c = 0; c < 64; ++c) {
    const float* wp = dw_w + (num * 64 + c) * 16;
    const float* qp = qb + c * 4096 + oy * 256 + ox * 4;
    float4 r0 = *(const float4*)(qp);
    float4 r1 = *(const float4*)(qp + 64);
    float4 r2 = *(const float4*)(qp + 128);
    float4 r3 = *(const float4*)(qp + 192);
    float s = dw_b[num * 64 + c];
    s += wp[0] * r0.x + wp[1] * r0.y + wp[2] * r0.z + wp[3] * r0.w;
    s += wp[4] * r1.x + wp[5] * r1.y + wp[6] * r1.z + wp[7] * r1.w;
    s += wp[8] * r2.x + wp[9] * r2.y + wp[10] * r2.z + wp[11] * r2.w;
    s += wp[12] * r3.x + wp[13] * r3.y + wp[14] * r3.z + wp[15] * r3.w;
    off[c] = s;
    sum += s;
    sumsq += s * s;
  }
  float mu = sum * 0.015625f;
  float var = sumsq * 0.015625f - mu * mu;
  float rstd = rsqrtf(var + 1e-5f);
  float offy = 0.f, offx = 0.f;
#pragma unroll
  for (int c = 0; c < 64; ++c) {
    float g = (off[c] - mu) * rstd * ln_g[num * 64 + c] + ln_b[num * 64 + c];
    g = 0.5f * g * (1.f + erff(g * 0.70710678118654752f));  // exact gelu
    offy += pw_w[num * 128 + c] * g;
    offx += pw_w[num * 128 + 64 + c] * g;
  }
  float ref_y = (0.5f + (float)oy) * (2.f / 15.f) - 1.f;
  float ref_x = (0.5f + (float)ox) * (2.f / 15.f) - 1.f;
  float py = fminf(fmaxf(offy + ref_y, -1.f), 1.f);
  float px = fminf(fmaxf(offx + ref_x, -1.f), 1.f);
  pos_buf[(wg * 256 + n) * 2 + 0] = py;
  pos_buf[(wg * 256 + n) * 2 + 1] = px;
}

// ------------- bilinear sample kv (align_corners=True) -> xs[num][b][c][n]
__global__ __launch_bounds__(256) void k_sample(
    const float* __restrict__ x0, const float* __restrict__ x1,
    const float* __restrict__ pos_buf, float* __restrict__ xs_buf) {
  int wg = blockIdx.x;
  int cg = wg & 7;
  int b = (wg >> 3) & 7;
  int num = wg >> 6;
  const float* xj = (num == 2) ? x1 : x0;       // kv source: x0,x0,x1
  int n = threadIdx.x;
  int nb = num * 8 + b;
  float py = pos_buf[(nb * 256 + n) * 2 + 0];
  float px = pos_buf[(nb * 256 + n) * 2 + 1];
  float fy = (py + 1.f) * 31.5f;                // (g+1)*0.5*(64-1)
  float fx = (px + 1.f) * 31.5f;
  float y0f = floorf(fy), x0f = floorf(fx);
  float wy = fy - y0f, wx = fx - x0f;
  int y0 = (int)y0f, xi0 = (int)x0f;
  int y1 = min(y0 + 1, 63), xi1 = min(xi0 + 1, 63);  // OOB tap has weight 0
  float w00 = (1.f - wy) * (1.f - wx), w01 = (1.f - wy) * wx;
  float w10 = wy * (1.f - wx), w11 = wy * wx;
  const float* xb = xj + b * 524288;
#pragma unroll
  for (int cc = 0; cc < 8; ++cc) {
    int c = cg * 8 + cc;
    const float* p = xb + c * 4096;
    float v = w00 * p[y0 * 64 + xi0] + w01 * p[y0 * 64 + xi1] +
              w10 * p[y1 * 64 + xi0] + w11 * p[y1 * 64 + xi1];
    xs_buf[(nb * 64 + c) * 256 + n] = v;
  }
}

// -------------------------------- k = pk_w@xs + pk_b ; v = pv_w@xs + pv_b
__global__ __launch_bounds__(256) void k_kv(
    const float* __restrict__ xs_buf, const float* __restrict__ pk_w,
    const float* __restrict__ pk_b, const float* __restrict__ pv_w,
    const float* __restrict__ pv_b, float* __restrict__ k_buf,
    float* __restrict__ v_buf) {
  int wg = blockIdx.x;
  int which = wg & 1;
  int nb = wg >> 1;
  int num = nb >> 3;
  const float* w = (which ? pv_w : pk_w) + num * 4096;
  const float* bias = (which ? pv_b : pk_b) + num * 64;
  float* ob = (which ? v_buf : k_buf) + nb * 64 * 256;
  const float* xsb = xs_buf + nb * 64 * 256;
  int n = threadIdx.x;
  float acc[64];
#pragma unroll
  for (int o = 0; o < 64; ++o) acc[o] = 0.f;
  for (int c = 0; c < 64; ++c) {
    float xv = xsb[c * 256 + n];
#pragma unroll
    for (int o = 0; o < 64; ++o) acc[o] += w[o * 64 + c] * xv;  // s_loads
  }
#pragma unroll
  for (int o = 0; o < 64; ++o) ob[o * 256 + n] = acc[o] + bias[o];
}

// -------- pad rpe tables 127x127 -> 128x128 (dup last row/col): removes all
// clamp logic in k_attn; taps become base + imm offsets.
// NOTE: tpad ALIASES xs_buf (dead after k_kv) so ws footprint stays at the
// round-0-proven 29.93 MB — growing ws caused the round-2 device fault.
__global__ __launch_bounds__(128) void k_padrpe(
    const float* __restrict__ rpe, float* __restrict__ tpad) {
  int wg = blockIdx.x;              // 12 tables * 128 rows
  int tbl = wg >> 7;
  int r = wg & 127;
  int c = threadIdx.x;
  int rs = min(r, 126), cs = min(c, 126);
  tpad[tbl * 16384 + r * 128 + c] = rpe[tbl * 16129 + rs * 127 + cs];
}

// ----------------- MFMA attention. S^T = K_A . Q_B  (16x16x16 f16):
// C-layout of S^T (n=quad*4+reg, m=lane&15) == B-frag layout for PV
// (O^T = V_A . P^T_B), so no transpose round-trip is needed.
// grid 1536 = num(3)*b(8)*h(4)*mblock(16); 4 waves, each 4 m-tiles of 16.
//
// Bias table: this block touches exactly rows [mblock*4, mblock*4+67] x
// cols [0,127] of the padded table (my-mblock*4==wave, mx==mt*16+l15,
// iy,ix in [0,63]); stage that 68x128 window in LDS with row stride
// padded to 132 floats (33 float4 -> 16B-aligned rows, and bank =
// (4*(wave+iy)+col)&31 decorrelates the 4 quads' tap runs).
//
// Round-2 lesson: forcing __launch_bounds__(256,3) with persistent
// kf[16]/vf[16] arrays spilled 64 VGPRs to scratch (WRITE_SIZE 24MB->530MB,
// 2.5x regression). Fix is structural: LOOP INTERCHANGE (t outer, mt inner)
// so no 16-entry fragment array persists. Per-t state: one kf + one vf;
// persistent: qf[4]+O[4]+L[4] (~28 regs), all statically indexed.
// No forced occupancy cap.
__global__ __launch_bounds__(256) void k_attn(
    float* __restrict__ q_buf, const float* __restrict__ k_buf,
    const float* __restrict__ v_buf, const float* __restrict__ pos_buf,
    const float* __restrict__ tpad) {
  int wg = blockIdx.x;
  int mblock = wg & 15;
  int h = (wg >> 4) & 3;
  int b = (wg >> 6) & 7;
  int num = wg >> 9;
  int nb = num * 8 + b;
  int tid = threadIdx.x;
  int lane = tid & 63;
  int wave = __builtin_amdgcn_readfirstlane(tid >> 6);
  int l15 = lane & 15;
  int quad = lane >> 4;

  __shared__ float4 s_kp[256];
  __shared__ __align__(16) float s_T[68 * 132];   // 35,904 B

  // stage the block's table window: rows mblock*4 .. mblock*4+67 (68x128),
  // dst stride 132. Source base is a multiple of 512 floats -> 16B aligned;
  // max source float idx = 11*16384 + 15*512 + 8703 = 196607 (tpad end).
  {
    const float4* Ts = (const float4*)(tpad + (num * 4 + h) * 16384 + mblock * 512);
    float4* Td = (float4*)s_T;
#pragma unroll
    for (int i = 0; i < 8; ++i) {
      int idx = tid + i * 256;
      Td[idx + (idx >> 5)] = Ts[idx];    // row*33 + col32
    }
    if (tid < 128) {
      int idx = tid + 2048;              // 2176 = 8.5*256 total
      Td[idx + (idx >> 5)] = Ts[idx];
    }
  }

  // per-key bilinear params: table coord t = m + 31.5*(1-pos); store the
  // tap's LDS float offset iy*132+ix (int bits) + fractional weights.
  {
    float py = pos_buf[(nb * 256 + tid) * 2 + 0];
    float px = pos_buf[(nb * 256 + tid) * 2 + 1];
    float by = 31.5f * (1.f - py);
    float bx = 31.5f * (1.f - px);
    float iyf = floorf(by), ixf = floorf(bx);
    float4 kp;
    kp.x = __int_as_float((int)iyf * 132 + (int)ixf);
    kp.y = by - iyf;                  // wy
    kp.z = bx - ixf;                  // wx
    kp.w = 0.f;
    s_kp[tid] = kp;
  }
  __syncthreads();

  int hc = nb * 64 + h * 16;
  const float* kb = k_buf + hc * 256;
  const float* vb = v_buf + hc * 256;
  float* qb = q_buf + hc * 4096;
  const float* Trow = s_T + wave * 132 + l15;   // + mt*16 + tap offset

  // persistent per-mt state (statically indexed everywhere)
  f16x4 qf[4];
  f32x4 O[4];
  float L[4];
#pragma unroll
  for (int mt = 0; mt < 4; ++mt) {
    int m = mblock * 256 + wave * 64 + mt * 16 + l15;
#pragma unroll
    for (int j = 0; j < 4; ++j)
      qf[mt][j] = (_Float16)qb[(quad * 4 + j) * 4096 + m];  // B[c][m]
    O[mt][0] = 0.f; O[mt][1] = 0.f; O[mt][2] = 0.f; O[mt][3] = 0.f;
    L[mt] = 0.f;
  }

#pragma unroll 2
  for (int t = 0; t < 16; ++t) {
    // K frag: A[n][c]: n = t*16 + l15, c = quad*4+j
    f16x4 kf;
#pragma unroll
    for (int j = 0; j < 4; ++j)
      kf[j] = (_Float16)kb[(quad * 4 + j) * 256 + t * 16 + l15];
    // V frag: A[c][n]: c = l15, n = t*16 + quad*4+j -> contiguous float4
    float4 vv = *(const float4*)(vb + l15 * 256 + t * 16 + quad * 4);
    f16x4 vf;
    vf[0] = (_Float16)vv.x; vf[1] = (_Float16)vv.y;
    vf[2] = (_Float16)vv.z; vf[3] = (_Float16)vv.w;

    f32x4 S[4];
#pragma unroll
    for (int mt = 0; mt < 4; ++mt) {
      f32x4 Z = {0.f, 0.f, 0.f, 0.f};
      S[mt] = __builtin_amdgcn_mfma_f32_16x16x16f16(kf, qf[mt], Z, 0, 0, 0);
    }

    f16x4 pf[4];
#pragma unroll
    for (int r = 0; r < 4; ++r) {
      float4 kp = s_kp[t * 16 + quad * 4 + r];
      int off = __float_as_int(kp.x);
#pragma unroll
      for (int mt = 0; mt < 4; ++mt) {
        const float* p = Trow + mt * 16 + off;
        float t00 = p[0], t01 = p[1], t10 = p[132], t11 = p[133];
        float lx0 = fmaf(kp.z, t01 - t00, t00);
        float lx1 = fmaf(kp.z, t11 - t10, t10);
        float bias = fmaf(kp.y, lx1 - lx0, lx0);
        float s = fminf(fmaf(S[mt][r], 0.25f, bias), 10.f);  // logits << 10
        float e = __expf(s);
        L[mt] += e;
        pf[mt][r] = (_Float16)e;
      }
    }
#pragma unroll
    for (int mt = 0; mt < 4; ++mt)
      O[mt] = __builtin_amdgcn_mfma_f32_16x16x16f16(vf, pf[mt], O[mt], 0, 0, 0);
  }

#pragma unroll
  for (int mt = 0; mt < 4; ++mt) {
    float Lm = L[mt];
    Lm += __shfl_xor(Lm, 16);
    Lm += __shfl_xor(Lm, 32);
    float rinv = 1.f / Lm;
    int m = mblock * 256 + wave * 64 + mt * 16 + l15;
#pragma unroll
    for (int r = 0; r < 4; ++r)
      qb[(quad * 4 + r) * 4096 + m] = O[mt][r] * rinv;  // in-place over q
  }
}

// ------------------- po conv, out[l][b][64+o][p] = x_copy + sum_num conv
// Round-3 change: NO ATOMICS. Grid 256 = l(2) * b(8) * tile(16). A level-1
// block accumulates num=0; a level-2 block loops num in {1,2}, accumulating
// both contributions in registers across two passes of the LDS-staged
// cc-loop. Epilogue: plain load (out holds the k_copy'd x) + add + store.
// Removes 6.3M device-scope atomicAdds (WRITE_SIZE was 6x the output size).
__global__ __launch_bounds__(256) void k_po(
    const float* __restrict__ attn_buf, const float* __restrict__ po_w,
    const float* __restrict__ po_b, float* __restrict__ out) {
  int wg = blockIdx.x;
  int tile = wg & 15;
  int b = (wg >> 4) & 7;
  int l = (wg >> 7) + 1;                        // 1 or 2
  int p0 = tile * 256;
  int lane = threadIdx.x & 63;
  int og = __builtin_amdgcn_readfirstlane(threadIdx.x >> 6);
  int o0 = og * 16;
  __shared__ float lx[16 * 256];
  float acc[4][16];
#pragma unroll
  for (int j = 0; j < 4; ++j)
#pragma unroll
    for (int i = 0; i < 16; ++i) acc[j][i] = 0.f;

  int nlo = (l == 1) ? 0 : 1;
  int nPasses = (l == 1) ? 1 : 2;
  for (int s = 0; s < nPasses; ++s) {
    int num = nlo + s;
    const float* abase = attn_buf + (num * 8 + b) * 64 * 4096;
    const float* w = po_w + num * 4096;
    for (int cc = 0; cc < 64; cc += 16) {
      __syncthreads();
#pragma unroll
      for (int r = 0; r < 4; ++r) {
        int c = (threadIdx.x >> 6) * 4 + r;
        *(float4*)(lx + c * 256 + lane * 4) =
            *(const float4*)(abase + (cc + c) * 4096 + p0 + lane * 4);
      }
      __syncthreads();
#pragma unroll
      for (int c = 0; c < 16; ++c) {
        float4 xv = *(const float4*)(lx + c * 256 + lane * 4);
#pragma unroll
        for (int i = 0; i < 16; ++i) {
          float wv = w[(o0 + i) * 64 + cc + c];
          acc[0][i] += xv.x * wv;
          acc[1][i] += xv.y * wv;
          acc[2][i] += xv.z * wv;
          acc[3][i] += xv.w * wv;
        }
      }
    }
  }

  float* ob = out + ((l * 8 + b) * 128 + 64) * 4096;
#pragma unroll
  for (int i = 0; i < 16; ++i) {
    int o = o0 + i;
    float bias = po_b[nlo * 64 + o];
    if (l == 2) bias += po_b[128 + o];
    float4 cur = *(const float4*)(ob + o * 4096 + p0 + lane * 4);
    float4 r;
    r.x = cur.x + acc[0][i] + bias;
    r.y = cur.y + acc[1][i] + bias;
    r.z = cur.z + acc[2][i] + bias;
    r.w = cur.w + acc[3][i] + bias;
    *(float4*)(ob + o * 4096 + p0 + lane * 4) = r;
  }
}

extern "C" void kernel_launch(void* const* d_in, const int* in_sizes, int n_in,
                              void* d_out, int out_size, void* d_ws,
                              size_t ws_size, hipStream_t stream) {
  const float* x0 = (const float*)d_in[0];
  const float* x1 = (const float*)d_in[1];
  const float* x2 = (const float*)d_in[2];
  const float* pq_w = (const float*)d_in[3];
  const float* pq_b = (const float*)d_in[4];
  const float* dw_w = (const float*)d_in[5];
  const float* dw_b = (const float*)d_in[6];
  const float* ln_g = (const float*)d_in[7];
  const float* ln_b = (const float*)d_in[8];
  const float* pw_w = (const float*)d_in[9];
  const float* pk_w = (const float*)d_in[10];
  const float* pk_b = (const float*)d_in[11];
  const float* pv_w = (const float*)d_in[12];
  const float* pv_b = (const float*)d_in[13];
  const float* po_w = (const float*)d_in[14];
  const float* po_b = (const float*)d_in[15];
  const float* rpe = (const float*)d_in[16];
  float* out = (float*)d_out;
  float* ws = (float*)d_ws;

  // ws layout (floats): q/attn (in-place) 6291456, pos 12288, xs 393216,
  // k 393216, v 393216 -> 29,933,568 bytes, IDENTICAL to round-0-proven size.
  // tpad (196608) aliases xs_buf: xs is dead after k_kv; k_padrpe runs after.
  float* q_buf = ws;
  float* pos_buf = q_buf + 6291456;
  float* xs_buf = pos_buf + 12288;
  float* k_buf = xs_buf + 393216;
  float* v_buf = k_buf + 393216;
  float* tpad = xs_buf;

  hipLaunchKernelGGL(k_copy, dim3(12288), dim3(256), 0, stream, x0, x1, x2, out);
  hipLaunchKernelGGL(k_qconv, dim3(384), dim3(256), 0, stream, x1, x2, pq_w,
                     pq_b, q_buf);
  hipLaunchKernelGGL(k_offset, dim3(24), dim3(256), 0, stream, q_buf, dw_w,
                     dw_b, ln_g, ln_b, pw_w, pos_buf);
  hipLaunchKernelGGL(k_sample, dim3(192), dim3(256), 0, stream, x0, x1,
                     pos_buf, xs_buf);
  hipLaunchKernelGGL(k_kv, dim3(48), dim3(256), 0, stream, xs_buf, pk_w, pk_b,
                     pv_w, pv_b, k_buf, v_buf);
  hipLaunchKernelGGL(k_padrpe, dim3(1536), dim3(128), 0, stream, rpe, tpad);
  hipLaunchKernelGGL(k_attn, dim3(1536), dim3(256), 0, stream, q_buf, k_buf,
                     v_buf, pos_buf, tpad);
  hipLaunchKernelGGL(k_po, dim3(256), dim3(256), 0, stream, q_buf, po_w, po_b,
                     out);
}

// Round 4
// 372.136 us; speedup vs baseline: 2.6072x; 1.0771x over previous
//
#include <hip/hip_runtime.h>
#include <math.h>

// Problem constants: B=8, C=128, H=W=64, NC=64, NH=4, HC=16, KS=4,
// Hk=Wk=16, Ns=256, HW=4096, NB=3 blocks: (i,j) = (1,0),(2,0),(2,1)

typedef _Float16 f16x4 __attribute__((ext_vector_type(4)));
typedef float f32x4 __attribute__((ext_vector_type(4)));

// ---------------------------------------------------------------- copy out=x
__global__ __launch_bounds__(256) void k_copy(
    const float* __restrict__ x0, const float* __restrict__ x1,
    const float* __restrict__ x2, float* __restrict__ out) {
  int i = blockIdx.x * 256 + threadIdx.x;       // float4 index, 3*1048576 total
  int lvl = i >> 20;
  int idx = i & 1048575;
  const float4* src = (lvl == 0) ? (const float4*)x0
                    : (lvl == 1) ? (const float4*)x1 : (const float4*)x2;
  ((float4*)out)[i] = src[idx];
}

// ------------------------------------------------- q = pq_w @ x_i[:, :64] + b
// Round-4: k_kv-style (no LDS, no barriers). Each thread owns ONE pixel
// column: per c, one coalesced load + 64 FMAs against s_loaded weights.
// The previous LDS-staged version ran at 1 wave/SIMD with 8 barriers/pass
// and was latency-bound (k_po round-3 counters: VALUBusy 20%, occ 8.5%).
__global__ __launch_bounds__(256) void k_qconv(
    const float* __restrict__ x1, const float* __restrict__ x2,
    const float* __restrict__ pq_w, const float* __restrict__ pq_b,
    float* __restrict__ q_buf) {
  int wg = blockIdx.x;            // 384 = num(3)*128 + b(8)*16 + tile(16)
  int tile = wg & 15;
  int b = (wg >> 4) & 7;
  int num = wg >> 7;
  const float* xin = (num == 0) ? x1 : x2;
  const float* xbase = xin + b * 524288;        // channels 0..63 used
  const float* w = pq_w + num * 4096;
  int px = tile * 256 + threadIdx.x;
  float acc[64];
#pragma unroll
  for (int o = 0; o < 64; ++o) acc[o] = 0.f;
  for (int c = 0; c < 64; ++c) {
    float xv = xbase[c * 4096 + px];            // coalesced
#pragma unroll
    for (int o = 0; o < 64; ++o) acc[o] += w[o * 64 + c] * xv;  // s_loads
  }
  float* qb = q_buf + (num * 8 + b) * 64 * 4096;
#pragma unroll
  for (int o = 0; o < 64; ++o)
    qb[o * 4096 + px] = acc[o] + pq_b[num * 64 + o];
}

// ---------------- offset head: depthwise 4x4 s4 + LN + GELU + proj -> pos
__global__ __launch_bounds__(256) void k_offset(
    const float* __restrict__ q_buf, const float* __restrict__ dw_w,
    const float* __restrict__ dw_b, const float* __restrict__ ln_g,
    const float* __restrict__ ln_b, const float* __restrict__ pw_w,
    float* __restrict__ pos_buf) {
  int wg = blockIdx.x;
  int num = wg >> 3;
  int n = threadIdx.x;
  int oy = n >> 4, ox = n & 15;
  const float* qb = q_buf + wg * 64 * 4096;
  float off[64];
  float sum = 0.f, sumsq = 0.f;
#pragma unroll
  for (int c = 0; c < 64; ++c) {
    const float* wp = dw_w + (num * 64 + c) * 16;
    const float* qp = qb + c * 4096 + oy * 256 + ox * 4;
    float4 r0 = *(const float4*)(qp);
    float4 r1 = *(const float4*)(qp + 64);
    float4 r2 = *(const float4*)(qp + 128);
    float4 r3 = *(const float4*)(qp + 192);
    float s = dw_b[num * 64 + c];
    s += wp[0] * r0.x + wp[1] * r0.y + wp[2] * r0.z + wp[3] * r0.w;
    s += wp[4] * r1.x + wp[5] * r1.y + wp[6] * r1.z + wp[7] * r1.w;
    s += wp[8] * r2.x + wp[9] * r2.y + wp[10] * r2.z + wp[11] * r2.w;
    s += wp[12] * r3.x + wp[13] * r3.y + wp[14] * r3.z + wp[15] * r3.w;
    off[c] = s;
    sum += s;
    sumsq += s * s;
  }
  float mu = sum * 0.015625f;
  float var = sumsq * 0.015625f - mu * mu;
  float rstd = rsqrtf(var + 1e-5f);
  float offy = 0.f, offx = 0.f;
#pragma unroll
  for (int c = 0; c < 64; ++c) {
    float g = (off[c] - mu) * rstd * ln_g[num * 64 + c] + ln_b[num * 64 + c];
    g = 0.5f * g * (1.f + erff(g * 0.70710678118654752f));  // exact gelu
    offy += pw_w[num * 128 + c] * g;
    offx += pw_w[num * 128 + 64 + c] * g;
  }
  float ref_y = (0.5f + (float)oy) * (2.f / 15.f) - 1.f;
  float ref_x = (0.5f + (float)ox) * (2.f / 15.f) - 1.f;
  float py = fminf(fmaxf(offy + ref_y, -1.f), 1.f);
  float px = fminf(fmaxf(offx + ref_x, -1.f), 1.f);
  pos_buf[(wg * 256 + n) * 2 + 0] = py;
  pos_buf[(wg * 256 + n) * 2 + 1] = px;
}

// ------------- bilinear sample kv (align_corners=True) -> xs[num][b][c][n]
__global__ __launch_bounds__(256) void k_sample(
    const float* __restrict__ x0, const float* __restrict__ x1,
    const float* __restrict__ pos_buf, float* __restrict__ xs_buf) {
  int wg = blockIdx.x;
  int cg = wg & 7;
  int b = (wg >> 3) & 7;
  int num = wg >> 6;
  const float* xj = (num == 2) ? x1 : x0;       // kv source: x0,x0,x1
  int n = threadIdx.x;
  int nb = num * 8 + b;
  float py = pos_buf[(nb * 256 + n) * 2 + 0];
  float px = pos_buf[(nb * 256 + n) * 2 + 1];
  float fy = (py + 1.f) * 31.5f;                // (g+1)*0.5*(64-1)
  float fx = (px + 1.f) * 31.5f;
  float y0f = floorf(fy), x0f = floorf(fx);
  float wy = fy - y0f, wx = fx - x0f;
  int y0 = (int)y0f, xi0 = (int)x0f;
  int y1 = min(y0 + 1, 63), xi1 = min(xi0 + 1, 63);  // OOB tap has weight 0
  float w00 = (1.f - wy) * (1.f - wx), w01 = (1.f - wy) * wx;
  float w10 = wy * (1.f - wx), w11 = wy * wx;
  const float* xb = xj + b * 524288;
#pragma unroll
  for (int cc = 0; cc < 8; ++cc) {
    int c = cg * 8 + cc;
    const float* p = xb + c * 4096;
    float v = w00 * p[y0 * 64 + xi0] + w01 * p[y0 * 64 + xi1] +
              w10 * p[y1 * 64 + xi0] + w11 * p[y1 * 64 + xi1];
    xs_buf[(nb * 64 + c) * 256 + n] = v;
  }
}

// -------------------------------- k = pk_w@xs + pk_b ; v = pv_w@xs + pv_b
__global__ __launch_bounds__(256) void k_kv(
    const float* __restrict__ xs_buf, const float* __restrict__ pk_w,
    const float* __restrict__ pk_b, const float* __restrict__ pv_w,
    const float* __restrict__ pv_b, float* __restrict__ k_buf,
    float* __restrict__ v_buf) {
  int wg = blockIdx.x;
  int which = wg & 1;
  int nb = wg >> 1;
  int num = nb >> 3;
  const float* w = (which ? pv_w : pk_w) + num * 4096;
  const float* bias = (which ? pv_b : pk_b) + num * 64;
  float* ob = (which ? v_buf : k_buf) + nb * 64 * 256;
  const float* xsb = xs_buf + nb * 64 * 256;
  int n = threadIdx.x;
  float acc[64];
#pragma unroll
  for (int o = 0; o < 64; ++o) acc[o] = 0.f;
  for (int c = 0; c < 64; ++c) {
    float xv = xsb[c * 256 + n];
#pragma unroll
    for (int o = 0; o < 64; ++o) acc[o] += w[o * 64 + c] * xv;  // s_loads
  }
#pragma unroll
  for (int o = 0; o < 64; ++o) ob[o * 256 + n] = acc[o] + bias[o];
}

// -------- pad rpe tables 127x127 -> 128x128 (dup last row/col): removes all
// clamp logic in k_attn; taps become base + imm offsets.
// NOTE: tpad ALIASES xs_buf (dead after k_kv) so ws footprint stays at the
// round-0-proven 29.93 MB — growing ws caused the round-2 device fault.
__global__ __launch_bounds__(128) void k_padrpe(
    const float* __restrict__ rpe, float* __restrict__ tpad) {
  int wg = blockIdx.x;              // 12 tables * 128 rows
  int tbl = wg >> 7;
  int r = wg & 127;
  int c = threadIdx.x;
  int rs = min(r, 126), cs = min(c, 126);
  tpad[tbl * 16384 + r * 128 + c] = rpe[tbl * 16129 + rs * 127 + cs];
}

// ----------------- MFMA attention. S^T = K_A . Q_B  (16x16x16 f16):
// C-layout of S^T (n=quad*4+reg, m=lane&15) == B-frag layout for PV
// (O^T = V_A . P^T_B), so no transpose round-trip is needed.
// grid 1536 = num(3)*b(8)*h(4)*mblock(16); 4 waves, each 4 m-tiles of 16.
//
// Bias table: this block touches exactly rows [mblock*4, mblock*4+67] x
// cols [0,127] of the padded table (my-mblock*4==wave, mx==mt*16+l15,
// iy,ix in [0,63]); stage that 68x128 window in LDS with row stride
// padded to 132 floats (33 float4 -> 16B-aligned rows, and bank =
// (4*(wave+iy)+col)&31 decorrelates the 4 quads' tap runs).
//
// Round-2 lesson: forcing __launch_bounds__(256,3) with persistent
// kf[16]/vf[16] arrays spilled 64 VGPRs to scratch (WRITE_SIZE 24MB->530MB,
// 2.5x regression). Fix is structural: LOOP INTERCHANGE (t outer, mt inner)
// so no 16-entry fragment array persists. Per-t state: one kf + one vf;
// persistent: qf[4]+O[4]+L[4] (~28 regs), all statically indexed.
// No forced occupancy cap.
__global__ __launch_bounds__(256) void k_attn(
    float* __restrict__ q_buf, const float* __restrict__ k_buf,
    const float* __restrict__ v_buf, const float* __restrict__ pos_buf,
    const float* __restrict__ tpad) {
  int wg = blockIdx.x;
  int mblock = wg & 15;
  int h = (wg >> 4) & 3;
  int b = (wg >> 6) & 7;
  int num = wg >> 9;
  int nb = num * 8 + b;
  int tid = threadIdx.x;
  int lane = tid & 63;
  int wave = __builtin_amdgcn_readfirstlane(tid >> 6);
  int l15 = lane & 15;
  int quad = lane >> 4;

  __shared__ float4 s_kp[256];
  __shared__ __align__(16) float s_T[68 * 132];   // 35,904 B

  // stage the block's table window: rows mblock*4 .. mblock*4+67 (68x128),
  // dst stride 132. Source base is a multiple of 512 floats -> 16B aligned;
  // max source float idx = 11*16384 + 15*512 + 8703 = 196607 (tpad end).
  {
    const float4* Ts = (const float4*)(tpad + (num * 4 + h) * 16384 + mblock * 512);
    float4* Td = (float4*)s_T;
#pragma unroll
    for (int i = 0; i < 8; ++i) {
      int idx = tid + i * 256;
      Td[idx + (idx >> 5)] = Ts[idx];    // row*33 + col32
    }
    if (tid < 128) {
      int idx = tid + 2048;              // 2176 = 8.5*256 total
      Td[idx + (idx >> 5)] = Ts[idx];
    }
  }

  // per-key bilinear params: table coord t = m + 31.5*(1-pos); store the
  // tap's LDS float offset iy*132+ix (int bits) + fractional weights.
  {
    float py = pos_buf[(nb * 256 + tid) * 2 + 0];
    float px = pos_buf[(nb * 256 + tid) * 2 + 1];
    float by = 31.5f * (1.f - py);
    float bx = 31.5f * (1.f - px);
    float iyf = floorf(by), ixf = floorf(bx);
    float4 kp;
    kp.x = __int_as_float((int)iyf * 132 + (int)ixf);
    kp.y = by - iyf;                  // wy
    kp.z = bx - ixf;                  // wx
    kp.w = 0.f;
    s_kp[tid] = kp;
  }
  __syncthreads();

  int hc = nb * 64 + h * 16;
  const float* kb = k_buf + hc * 256;
  const float* vb = v_buf + hc * 256;
  float* qb = q_buf + hc * 4096;
  const float* Trow = s_T + wave * 132 + l15;   // + mt*16 + tap offset

  // persistent per-mt state (statically indexed everywhere)
  f16x4 qf[4];
  f32x4 O[4];
  float L[4];
#pragma unroll
  for (int mt = 0; mt < 4; ++mt) {
    int m = mblock * 256 + wave * 64 + mt * 16 + l15;
#pragma unroll
    for (int j = 0; j < 4; ++j)
      qf[mt][j] = (_Float16)qb[(quad * 4 + j) * 4096 + m];  // B[c][m]
    O[mt][0] = 0.f; O[mt][1] = 0.f; O[mt][2] = 0.f; O[mt][3] = 0.f;
    L[mt] = 0.f;
  }

#pragma unroll 2
  for (int t = 0; t < 16; ++t) {
    // K frag: A[n][c]: n = t*16 + l15, c = quad*4+j
    f16x4 kf;
#pragma unroll
    for (int j = 0; j < 4; ++j)
      kf[j] = (_Float16)kb[(quad * 4 + j) * 256 + t * 16 + l15];
    // V frag: A[c][n]: c = l15, n = t*16 + quad*4+j -> contiguous float4
    float4 vv = *(const float4*)(vb + l15 * 256 + t * 16 + quad * 4);
    f16x4 vf;
    vf[0] = (_Float16)vv.x; vf[1] = (_Float16)vv.y;
    vf[2] = (_Float16)vv.z; vf[3] = (_Float16)vv.w;

    f32x4 S[4];
#pragma unroll
    for (int mt = 0; mt < 4; ++mt) {
      f32x4 Z = {0.f, 0.f, 0.f, 0.f};
      S[mt] = __builtin_amdgcn_mfma_f32_16x16x16f16(kf, qf[mt], Z, 0, 0, 0);
    }

    f16x4 pf[4];
#pragma unroll
    for (int r = 0; r < 4; ++r) {
      float4 kp = s_kp[t * 16 + quad * 4 + r];
      int off = __float_as_int(kp.x);
#pragma unroll
      for (int mt = 0; mt < 4; ++mt) {
        const float* p = Trow + mt * 16 + off;
        float t00 = p[0], t01 = p[1], t10 = p[132], t11 = p[133];
        float lx0 = fmaf(kp.z, t01 - t00, t00);
        float lx1 = fmaf(kp.z, t11 - t10, t10);
        float bias = fmaf(kp.y, lx1 - lx0, lx0);
        float s = fminf(fmaf(S[mt][r], 0.25f, bias), 10.f);  // logits << 10
        float e = __expf(s);
        L[mt] += e;
        pf[mt][r] = (_Float16)e;
      }
    }
#pragma unroll
    for (int mt = 0; mt < 4; ++mt)
      O[mt] = __builtin_amdgcn_mfma_f32_16x16x16f16(vf, pf[mt], O[mt], 0, 0, 0);
  }

#pragma unroll
  for (int mt = 0; mt < 4; ++mt) {
    float Lm = L[mt];
    Lm += __shfl_xor(Lm, 16);
    Lm += __shfl_xor(Lm, 32);
    float rinv = 1.f / Lm;
    int m = mblock * 256 + wave * 64 + mt * 16 + l15;
#pragma unroll
    for (int r = 0; r < 4; ++r)
      qb[(quad * 4 + r) * 4096 + m] = O[mt][r] * rinv;  // in-place over q
  }
}

// ------------------- po conv, out[l][b][64+o][p] += sum_num conv + bias
// Round-4: k_kv-style (no LDS, no barriers, no atomics). Grid 256 =
// l(2)*128 + b(8)*16 + tile(16). Each thread owns ONE pixel column; a
// level-2 block loops num in {1,2} into the same 64-deep register acc.
// Per c: one coalesced load + 64 FMAs against s_loaded weights. The
// round-3 LDS-staged version was latency-bound at 1 wave/SIMD
// (VALUBusy 20%, occ 8.5%, 95.7 us) — this is pure VALU with long
// independent-load runs, the pattern proven by k_kv.
__global__ __launch_bounds__(256) void k_po(
    const float* __restrict__ attn_buf, const float* __restrict__ po_w,
    const float* __restrict__ po_b, float* __restrict__ out) {
  int wg = blockIdx.x;
  int tile = wg & 15;
  int b = (wg >> 4) & 7;
  int l = (wg >> 7) + 1;                        // 1 or 2
  int px = tile * 256 + threadIdx.x;
  float acc[64];
#pragma unroll
  for (int o = 0; o < 64; ++o) acc[o] = 0.f;

  int nlo = (l == 1) ? 0 : 1;
  int nPasses = (l == 1) ? 1 : 2;
  for (int s = 0; s < nPasses; ++s) {
    int num = nlo + s;
    const float* abase = attn_buf + (num * 8 + b) * 64 * 4096;
    const float* w = po_w + num * 4096;
    for (int c = 0; c < 64; ++c) {
      float xv = abase[c * 4096 + px];          // coalesced
#pragma unroll
      for (int o = 0; o < 64; ++o) acc[o] += w[o * 64 + c] * xv;  // s_loads
    }
  }

  float* ob = out + ((l * 8 + b) * 128 + 64) * 4096;
#pragma unroll
  for (int o = 0; o < 64; ++o) {
    float bias = po_b[nlo * 64 + o];
    if (l == 2) bias += po_b[128 + o];
    ob[o * 4096 + px] += acc[o] + bias;         // plain RMW, conflict-free
  }
}

extern "C" void kernel_launch(void* const* d_in, const int* in_sizes, int n_in,
                              void* d_out, int out_size, void* d_ws,
                              size_t ws_size, hipStream_t stream) {
  const float* x0 = (const float*)d_in[0];
  const float* x1 = (const float*)d_in[1];
  const float* x2 = (const float*)d_in[2];
  const float* pq_w = (const float*)d_in[3];
  const float* pq_b = (const float*)d_in[4];
  const float* dw_w = (const float*)d_in[5];
  const float* dw_b = (const float*)d_in[6];
  const float* ln_g = (const float*)d_in[7];
  const float* ln_b = (const float*)d_in[8];
  const float* pw_w = (const float*)d_in[9];
  const float* pk_w = (const float*)d_in[10];
  const float* pk_b = (const float*)d_in[11];
  const float* pv_w = (const float*)d_in[12];
  const float* pv_b = (const float*)d_in[13];
  const float* po_w = (const float*)d_in[14];
  const float* po_b = (const float*)d_in[15];
  const float* rpe = (const float*)d_in[16];
  float* out = (float*)d_out;
  float* ws = (float*)d_ws;

  // ws layout (floats): q/attn (in-place) 6291456, pos 12288, xs 393216,
  // k 393216, v 393216 -> 29,933,568 bytes, IDENTICAL to round-0-proven size.
  // tpad (196608) aliases xs_buf: xs is dead after k_kv; k_padrpe runs after.
  float* q_buf = ws;
  float* pos_buf = q_buf + 6291456;
  float* xs_buf = pos_buf + 12288;
  float* k_buf = xs_buf + 393216;
  float* v_buf = k_buf + 393216;
  float* tpad = xs_buf;

  hipLaunchKernelGGL(k_copy, dim3(12288), dim3(256), 0, stream, x0, x1, x2, out);
  hipLaunchKernelGGL(k_qconv, dim3(384), dim3(256), 0, stream, x1, x2, pq_w,
                     pq_b, q_buf);
  hipLaunchKernelGGL(k_offset, dim3(24), dim3(256), 0, stream, q_buf, dw_w,
                     dw_b, ln_g, ln_b, pw_w, pos_buf);
  hipLaunchKernelGGL(k_sample, dim3(192), dim3(256), 0, stream, x0, x1,
                     pos_buf, xs_buf);
  hipLaunchKernelGGL(k_kv, dim3(48), dim3(256), 0, stream, xs_buf, pk_w, pk_b,
                     pv_w, pv_b, k_buf, v_buf);
  hipLaunchKernelGGL(k_padrpe, dim3(1536), dim3(128), 0, stream, rpe, tpad);
  hipLaunchKernelGGL(k_attn, dim3(1536), dim3(256), 0, stream, q_buf, k_buf,
                     v_buf, pos_buf, tpad);
  hipLaunchKernelGGL(k_po, dim3(256), dim3(256), 0, stream, q_buf, po_w, po_b,
                     out);
}